// Round 1
// baseline (923.146 us; speedup 1.0000x reference)
//
#include <hip/hip_runtime.h>

// ---------------------------------------------------------------------------
// TemporalAttentionModule: B=64, C=2048, T=256, H=8, D=256 (== T)
//   q/k/v = W @ x + b   (per-batch GEMM, K=2048)
//   attn  = softmax(q k^T / 16);  out = attn @ v  -> (B, C, T) fp32
//
// ws layout (bytes):
//   [0,            67108864)  xT  bf16 [B][T][C]   (x transposed, k-major)
//   [67108864,     92274688)  Wbf bf16 [3][C][C]
//   [92274688,    293601280)  qkv bf16 [3][B][H][T][D]  (all stored d-major;
//                             for V this is V^T so PV is also a gemm_bt)
//
// proj_kernel: 256x256-tile 8-phase schedule (T2 st_16x32 swizzle +
// T3/T4 counted vmcnt + T5 setprio), 512 threads, 128 KiB LDS, 1 block/CU.
// ---------------------------------------------------------------------------

typedef __attribute__((ext_vector_type(8))) short    bf16x8;
typedef __attribute__((ext_vector_type(4))) float    f32x4;
typedef __attribute__((ext_vector_type(4))) unsigned short us4;
typedef __attribute__((ext_vector_type(8))) unsigned short us8;
typedef unsigned short u16;
typedef unsigned int   u32;

#define CC 2048
#define TT 256
#define BB 64
#define HH 8
#define DD 256

__device__ __forceinline__ u16 f2bf(float f) {
  u32 u = __builtin_bit_cast(u32, f);
  u32 r = (u + 0x7fffu + ((u >> 16) & 1u)) >> 16;
  return (u16)r;
}
__device__ __forceinline__ float bf2f(u16 b) {
  u32 u = ((u32)b) << 16;
  return __builtin_bit_cast(float, u);
}

__device__ __forceinline__ void async16(const void* g, void* l) {
  __builtin_amdgcn_global_load_lds(
      (const __attribute__((address_space(1))) u32*)g,
      (__attribute__((address_space(3))) u32*)l, 16, 0, 0);
}

// --------------------------- W fp32 -> bf16 --------------------------------
__global__ __launch_bounds__(256) void wconv_kernel(
    const float* __restrict__ w0, const float* __restrict__ w1,
    const float* __restrict__ w2, u16* __restrict__ dst) {
  int p = blockIdx.y;
  const float* s = (p == 0) ? w0 : (p == 1) ? w1 : w2;
  size_t i = ((size_t)blockIdx.x * 256 + threadIdx.x) * 4;
  float4 v = *(const float4*)(s + i);
  us4 o = {f2bf(v.x), f2bf(v.y), f2bf(v.z), f2bf(v.w)};
  *(us4*)(dst + (size_t)p * CC * CC + i) = o;
}

// ------------------ x (B,C,T) fp32 -> xT (B,T,C) bf16 ----------------------
__global__ __launch_bounds__(256) void xt_kernel(
    const float* __restrict__ x, u16* __restrict__ xT) {
  __shared__ float tile[64][68];
  int t0 = blockIdx.x * 64;
  int c0 = blockIdx.y * 64;
  int b  = blockIdx.z;
  int tid = threadIdx.x;
  int lr = tid >> 4;          // 0..15
  int lc = (tid & 15) * 4;    // t within tile
  const float* src = x + ((size_t)b * CC + c0) * TT + t0;
#pragma unroll
  for (int s = 0; s < 4; ++s) {
    int c = s * 16 + lr;
    float4 v = *(const float4*)(src + (size_t)c * TT + lc);
    *(float4*)&tile[c][lc] = v;
  }
  __syncthreads();
  int t  = tid >> 2;
  int cb = (tid & 3) * 16;
  u16 tmp[16];
#pragma unroll
  for (int e = 0; e < 16; ++e) tmp[e] = f2bf(tile[cb + e][t]);
  u16* dst = xT + ((size_t)b * TT + t0 + t) * CC + c0 + cb;
  *(us8*)dst       = *(const us8*)&tmp[0];
  *(us8*)(dst + 8) = *(const us8*)&tmp[8];
}

// --------------------- QKV projection GEMM (8-phase 256^2) -----------------
// Tile: 256(o) x 256(t), BK=64, 2 K-tiles per iteration, 8 phases.
// Waves: 8 (wm in {0,1} x wn in {0..3}); wave covers m rows {f*32+wm*16},
// n cols {g*64+wn*16} so quadrant (mh,nh) reads exactly LDS half-tiles.
// LDS: A/B double-buffered [2][256][64] bf16 each = 128 KiB.
// Swizzle st_16x32: byte ^= ((byte>>9)&1)<<5  (== col ^= ((row>>2)&1)<<4),
// applied on the READ address and inverted on the global staging SOURCE
// (global_load_lds dest must stay linear).
__global__ __launch_bounds__(512, 2) void proj_kernel(
    const u16* __restrict__ Wbf, const u16* __restrict__ xT,
    const float* __restrict__ bq, const float* __restrict__ bk,
    const float* __restrict__ bv, u16* __restrict__ qkv) {
  __shared__ __align__(16) u16 As[2][16384];
  __shared__ __align__(16) u16 Bs[2][16384];

  int tid = threadIdx.x;
  // XCD-aware bijective swizzle over 1536 = 8*192 blocks
  int bid = blockIdx.x;
  int wg  = (bid & 7) * 192 + (bid >> 3);
  int pm  = wg >> 6;            // 0..23 : proj*8 + mtile
  int b   = wg & 63;            // batch
  int proj = pm >> 3;
  int mt   = pm & 7;            // m-tile == head index
  int m0   = mt << 8;

  const u16* Ap = Wbf + (size_t)proj * CC * CC + (size_t)m0 * CC;
  const u16* Xp = xT + (size_t)b * TT * CC;
  const float* bias = (proj == 0) ? bq : (proj == 1) ? bk : bv;

  int lane = tid & 63, w = tid >> 6;
  int wm = w >> 2, wn = w & 3;
  int ar = lane & 15, kq = lane >> 4;

  // staging per-thread geometry: row r_b (0..63) within a 64-row slab,
  // 16B chunk c8; source chunk pre-swizzled (inverse of read swizzle)
  int r_b = tid >> 3;
  int c8  = tid & 7;
  int c8s = c8 ^ (((r_b >> 2) & 1) << 1);
  const size_t go = (size_t)r_b * CC + (size_t)c8s * 8;
  const int ldsq = r_b * 64 + c8 * 8;   // u16 units, + (h*2+j)*4096

  // read-side swizzled k-columns (in bf16 units): flip bit4 on ar&4
  const int csw  = ((ar >> 2) & 1) << 4;
  const int col0 = (kq * 8) ^ csw;      // kk=0 ; kk=1 is col0+32

  const int arow = wm * 16 + ar;        // + f*32
  const int brow = wn * 16 + ar;        // + g*64

#define STG_A(buf, kt, h)                                                     \
  do {                                                                        \
    async16(Ap + (size_t)((h) * 128) * CC + (size_t)(kt) * 64 + go,           \
            &As[buf][(h) * 8192 + ldsq]);                                     \
    async16(Ap + (size_t)((h) * 128 + 64) * CC + (size_t)(kt) * 64 + go,      \
            &As[buf][(h) * 8192 + 4096 + ldsq]);                              \
  } while (0)
#define STG_B(buf, kt, h)                                                     \
  do {                                                                        \
    async16(Xp + (size_t)((h) * 128) * CC + (size_t)(kt) * 64 + go,           \
            &Bs[buf][(h) * 8192 + ldsq]);                                     \
    async16(Xp + (size_t)((h) * 128 + 64) * CC + (size_t)(kt) * 64 + go,      \
            &Bs[buf][(h) * 8192 + 4096 + ldsq]);                              \
  } while (0)

  bf16x8 af[4][2], bfr[2][2];
  f32x4 acc[8][4] = {};

#define LDA(buf, mh)                                                          \
  do {                                                                        \
    _Pragma("unroll") for (int fl = 0; fl < 4; ++fl) {                        \
      int row = ((mh) * 4 + fl) * 32 + arow;                                  \
      af[fl][0] = *(const bf16x8*)&As[buf][row * 64 + col0];                  \
      af[fl][1] = *(const bf16x8*)&As[buf][row * 64 + col0 + 32];             \
    }                                                                         \
  } while (0)
#define LDB(buf, nh)                                                          \
  do {                                                                        \
    _Pragma("unroll") for (int gl = 0; gl < 2; ++gl) {                        \
      int row = ((nh) * 2 + gl) * 64 + brow;                                  \
      bfr[gl][0] = *(const bf16x8*)&Bs[buf][row * 64 + col0];                 \
      bfr[gl][1] = *(const bf16x8*)&Bs[buf][row * 64 + col0 + 32];            \
    }                                                                         \
  } while (0)
#define MMA(mh, nh)                                                           \
  do {                                                                        \
    _Pragma("unroll") for (int fl = 0; fl < 4; ++fl) {                        \
      _Pragma("unroll") for (int gl = 0; gl < 2; ++gl) {                      \
        acc[(mh) * 4 + fl][(nh) * 2 + gl] =                                   \
            __builtin_amdgcn_mfma_f32_16x16x32_bf16(                          \
                af[fl][0], bfr[gl][0], acc[(mh) * 4 + fl][(nh) * 2 + gl], 0,  \
                0, 0);                                                        \
        acc[(mh) * 4 + fl][(nh) * 2 + gl] =                                   \
            __builtin_amdgcn_mfma_f32_16x16x32_bf16(                          \
                af[fl][1], bfr[gl][1], acc[(mh) * 4 + fl][(nh) * 2 + gl], 0,  \
                0, 0);                                                        \
      }                                                                       \
    }                                                                         \
  } while (0)
#define PRE(buf, mh, nh)                                                      \
  do {                                                                        \
    if ((nh) == 0) LDA(buf, mh);                                              \
    LDB(buf, nh);                                                             \
  } while (0)
#define POST(mh, nh)                                                          \
  do {                                                                        \
    __builtin_amdgcn_s_barrier();                                             \
    asm volatile("s_waitcnt lgkmcnt(0)" ::: "memory");                        \
    __builtin_amdgcn_sched_barrier(0);                                        \
    __builtin_amdgcn_s_setprio(1);                                            \
    MMA(mh, nh);                                                              \
    __builtin_amdgcn_s_setprio(0);                                            \
    __builtin_amdgcn_sched_barrier(0);                                        \
    __builtin_amdgcn_s_barrier();                                             \
  } while (0)
#define VM4 asm volatile("s_waitcnt vmcnt(4)" ::: "memory")
#define VM0 asm volatile("s_waitcnt vmcnt(0)" ::: "memory")

  // prologue: kt0 fully (first 8 loads), then kt1 Ah0,Bh0
  STG_A(0, 0, 0); STG_B(0, 0, 0); STG_A(0, 0, 1); STG_B(0, 0, 1);
  STG_A(1, 1, 0); STG_B(1, 1, 0);
  VM4;                               // first 8 loads (kt0) landed
  __builtin_amdgcn_s_barrier();

  // main loop: iter i computes kt 2i (buf0, phases 1-4) and 2i+1 (buf1, 5-8).
  // Stage placement: each half-tile is overwritten >=1 full phase after its
  // last read; vmcnt(4) at p4/p8 proves the next K-tile landed.
  for (int i = 0; i < 15; ++i) {
    int k = 2 * i;
    PRE(0, 0, 0); STG_A(1, k + 1, 1);      POST(0, 0);   // p1
    PRE(0, 0, 1); STG_B(1, k + 1, 1);      POST(0, 1);   // p2
    PRE(0, 1, 0); STG_A(0, k + 2, 0);      POST(1, 0);   // p3
    PRE(0, 1, 1); STG_B(0, k + 2, 0); VM4; POST(1, 1);   // p4
    PRE(1, 0, 0); STG_A(0, k + 2, 1);      POST(0, 0);   // p5
    PRE(1, 0, 1); STG_B(0, k + 2, 1);      POST(0, 1);   // p6
    PRE(1, 1, 0); STG_A(1, k + 3, 0);      POST(1, 0);   // p7
    PRE(1, 1, 1); STG_B(1, k + 3, 0); VM4; POST(1, 1);   // p8
  }
  // peeled last iteration: kt30 (buf0), kt31 (buf1); finish kt31 staging
  PRE(0, 0, 0); STG_A(1, 31, 1);           POST(0, 0);
  PRE(0, 0, 1); STG_B(1, 31, 1);           POST(0, 1);
  PRE(0, 1, 0);                            POST(1, 0);
  PRE(0, 1, 1);                       VM0; POST(1, 1);
  PRE(1, 0, 0);                            POST(0, 0);
  PRE(1, 0, 1);                            POST(0, 1);
  PRE(1, 1, 0);                            POST(1, 0);
  PRE(1, 1, 1);                            POST(1, 1);

  // epilogue: C row (o) = f*32 + wm*16 + kq*4 + r ; col (t) = g*64 + wn*16 + ar
  // store transposed into qkv[proj][b][head=mt][t][d], bias added, bf16.
  u16* outp = qkv + (size_t)proj * BB * CC * TT +
              (size_t)(b * HH + mt) * TT * DD;
#pragma unroll
  for (int f = 0; f < 8; ++f) {
    int d0 = f * 32 + wm * 16 + kq * 4;
    float b0 = bias[m0 + d0],     b1 = bias[m0 + d0 + 1];
    float b2 = bias[m0 + d0 + 2], b3 = bias[m0 + d0 + 3];
#pragma unroll
    for (int g = 0; g < 4; ++g) {
      int t = g * 64 + wn * 16 + ar;
      f32x4 v = acc[f][g];
      us4 pk = {f2bf(v[0] + b0), f2bf(v[1] + b1), f2bf(v[2] + b2),
                f2bf(v[3] + b3)};
      *(us4*)(outp + (size_t)t * DD + d0) = pk;
    }
  }
#undef STG_A
#undef STG_B
#undef LDA
#undef LDB
#undef MMA
#undef PRE
#undef POST
#undef VM4
#undef VM0
}

// ----------------------------- fused attention -----------------------------
// block: one (b,h) pair, 64 q-rows. Phase1 S=QK^T in regs; exp (no max
// subtraction -- logits are O(1)); P bf16 -> padded LDS; rowsums via
// shfl_xor + LDS; Phase2 O = P V^T; epilogue multiplies by 1/rowsum.
__global__ __launch_bounds__(256) void attn_kernel(
    const u16* __restrict__ qkv, float* __restrict__ out) {
  __shared__ __align__(16) u16 As[64 * 32];
  __shared__ __align__(16) u16 Bs[256 * 32];
  __shared__ __align__(16) u16 Ps[64 * 264];   // +8 pad: 2-way banks only
  __shared__ float rowpart[64][4];
  __shared__ float inv[64];

  int tid = threadIdx.x;
  int i0 = blockIdx.x * 64;
  int bh = blockIdx.y;                          // b*8 + h
  const size_t hd = (size_t)TT * DD;            // 65536
  const u16* Q = qkv + (size_t)bh * hd;
  const u16* K = qkv + (size_t)(BB * HH + bh) * hd;
  const u16* V = qkv + (size_t)(2 * BB * HH + bh) * hd;

  int lane = tid & 63, w = tid >> 6;
  int ar = lane & 15, kq = lane >> 4;
  int arow = tid >> 2, acol = (tid & 3) * 8;

  const u16* Qbase = Q + (size_t)(i0 + arow) * DD + acol;
  const u16* Kbase = K + (size_t)arow * DD + acol;
  const u16* Vbase = V + (size_t)arow * DD + acol;

  f32x4 acc[4][4] = {};
  // ---- phase 1: S = Q K^T ----
  for (int k0 = 0; k0 < DD; k0 += 32) {
    async16(Qbase + k0, As + tid * 8);
#pragma unroll
    for (int s = 0; s < 4; ++s)
      async16(Kbase + (size_t)(s * 64) * DD + k0, Bs + s * 2048 + tid * 8);
    __syncthreads();
    bf16x8 af[4], bfv[4];
#pragma unroll
    for (int mt = 0; mt < 4; ++mt)
      af[mt] = *(const bf16x8*)&As[(mt * 16 + ar) * 32 + kq * 8];
#pragma unroll
    for (int nt = 0; nt < 4; ++nt)
      bfv[nt] = *(const bf16x8*)&Bs[(w * 64 + nt * 16 + ar) * 32 + kq * 8];
#pragma unroll
    for (int mt = 0; mt < 4; ++mt)
#pragma unroll
      for (int nt = 0; nt < 4; ++nt)
        acc[mt][nt] = __builtin_amdgcn_mfma_f32_16x16x32_bf16(
            af[mt], bfv[nt], acc[mt][nt], 0, 0, 0);
    __syncthreads();
  }
  // ---- exp + P to LDS + row partial sums ----
  const float scale = 0.0625f;
#pragma unroll
  for (int mt = 0; mt < 4; ++mt) {
    float ps[4] = {0.f, 0.f, 0.f, 0.f};
#pragma unroll
    for (int nt = 0; nt < 4; ++nt) {
      f32x4 v = acc[mt][nt];
#pragma unroll
      for (int r = 0; r < 4; ++r) {
        float p = __expf(v[r] * scale);
        u16 pb = f2bf(p);
        Ps[(mt * 16 + kq * 4 + r) * 264 + (w * 64 + nt * 16 + ar)] = pb;
        ps[r] += bf2f(pb);   // sum the rounded value for consistency
      }
    }
#pragma unroll
    for (int r = 0; r < 4; ++r) {
      float s = ps[r];
      s += __shfl_xor(s, 1, 64);
      s += __shfl_xor(s, 2, 64);
      s += __shfl_xor(s, 4, 64);
      s += __shfl_xor(s, 8, 64);
      if (ar == 0) rowpart[mt * 16 + kq * 4 + r][w] = s;
    }
  }
  __syncthreads();
  if (tid < 64) {
    float s = rowpart[tid][0] + rowpart[tid][1] + rowpart[tid][2] +
              rowpart[tid][3];
    inv[tid] = 1.0f / s;
  }
  // ---- phase 2: O = P V^T ----
#pragma unroll
  for (int mt = 0; mt < 4; ++mt)
#pragma unroll
    for (int nt = 0; nt < 4; ++nt) acc[mt][nt] = (f32x4){0.f, 0.f, 0.f, 0.f};
  for (int k0 = 0; k0 < TT; k0 += 32) {
#pragma unroll
    for (int s = 0; s < 4; ++s)
      async16(Vbase + (size_t)(s * 64) * DD + k0, Bs + s * 2048 + tid * 8);
    __syncthreads();
    bf16x8 af[4], bfv[4];
#pragma unroll
    for (int mt = 0; mt < 4; ++mt)
      af[mt] = *(const bf16x8*)&Ps[(mt * 16 + ar) * 264 + k0 + kq * 8];
#pragma unroll
    for (int nt = 0; nt < 4; ++nt)
      bfv[nt] = *(const bf16x8*)&Bs[(w * 64 + nt * 16 + ar) * 32 + kq * 8];
#pragma unroll
    for (int mt = 0; mt < 4; ++mt)
#pragma unroll
      for (int nt = 0; nt < 4; ++nt)
        acc[mt][nt] = __builtin_amdgcn_mfma_f32_16x16x32_bf16(
            af[mt], bfv[nt], acc[mt][nt], 0, 0, 0);
    __syncthreads();
  }
  // ---- epilogue: normalize rows, store fp32 ----
  int b = bh >> 3, h = bh & 7;
  float* obase = out + ((size_t)b * CC + h * TT + i0) * TT;
#pragma unroll
  for (int mt = 0; mt < 4; ++mt)
#pragma unroll
    for (int r = 0; r < 4; ++r) {
      int m = mt * 16 + kq * 4 + r;
      float iv = inv[m];
#pragma unroll
      for (int nt = 0; nt < 4; ++nt) {
        int n = w * 64 + nt * 16 + ar;
        obase[(size_t)m * TT + n] = acc[mt][nt][r] * iv;
      }
    }
}

// ---------------------------------------------------------------------------
extern "C" void kernel_launch(void* const* d_in, const int* in_sizes, int n_in,
                              void* d_out, int out_size, void* d_ws,
                              size_t ws_size, hipStream_t stream) {
  const float* x  = (const float*)d_in[0];
  const float* Wq = (const float*)d_in[1];
  const float* bq = (const float*)d_in[2];
  const float* Wk = (const float*)d_in[3];
  const float* bk = (const float*)d_in[4];
  const float* Wv = (const float*)d_in[5];
  const float* bv = (const float*)d_in[6];
  float* out = (float*)d_out;

  char* ws = (char*)d_ws;
  u16* xT  = (u16*)ws;                               // 64 MiB
  u16* Wbf = (u16*)(ws + 67108864);                  // 24 MiB
  u16* qkv = (u16*)(ws + 67108864 + 25165824);       // 192 MiB

  wconv_kernel<<<dim3(4096, 3, 1), 256, 0, stream>>>(Wq, Wk, Wv, Wbf);
  xt_kernel<<<dim3(4, 32, 64), 256, 0, stream>>>(x, xT);
  proj_kernel<<<dim3(1536, 1, 1), 512, 0, stream>>>(Wbf, xT, bq, bk, bv, qkv);
  attn_kernel<<<dim3(4, 512, 1), 256, 0, stream>>>(qkv, out);
}

// Round 2
// 852.574 us; speedup vs baseline: 1.0828x; 1.0828x over previous
//
#include <hip/hip_runtime.h>

// ---------------------------------------------------------------------------
// TemporalAttentionModule: B=64, C=2048, T=256, H=8, D=256 (== T)
//   q/k/v = W @ x + b   (per-batch GEMM, K=2048)
//   attn  = softmax(q k^T / 16);  out = attn @ v  -> (B, C, T) fp32
//
// ws layout (bytes):
//   [0,            67108864)  xT  bf16 [B][T][C]   (x transposed, k-major)
//   [67108864,     92274688)  Wbf bf16 [3][C][C]
//   [92274688,    293601280)  qkv bf16 [3][B][H][T][D]  (all stored d-major;
//                             for V this is V^T so PV is also a gemm_bt)
//
// proj_kernel: 256x256-tile 8-phase schedule, 512 threads, 128 KiB LDS.
// LDS swizzle: FULL 3-bit chunk XOR (stored 16B-chunk = chunk ^ (row&7)) --
// gives exactly 8 lanes per 4-bank quad on every ds_read_b128 (the 8-cycle
// minimum). Round-0's 1-bit XOR only permuted chunks 0-3 and left the
// conflict count unchanged (5.03e7).
// ---------------------------------------------------------------------------

typedef __attribute__((ext_vector_type(8))) short    bf16x8;
typedef __attribute__((ext_vector_type(4))) float    f32x4;
typedef __attribute__((ext_vector_type(4))) unsigned short us4;
typedef __attribute__((ext_vector_type(8))) unsigned short us8;
typedef unsigned short u16;
typedef unsigned int   u32;

#define CC 2048
#define TT 256
#define BB 64
#define HH 8
#define DD 256

__device__ __forceinline__ u16 f2bf(float f) {
  u32 u = __builtin_bit_cast(u32, f);
  u32 r = (u + 0x7fffu + ((u >> 16) & 1u)) >> 16;
  return (u16)r;
}
__device__ __forceinline__ float bf2f(u16 b) {
  u32 u = ((u32)b) << 16;
  return __builtin_bit_cast(float, u);
}

__device__ __forceinline__ void async16(const void* g, void* l) {
  __builtin_amdgcn_global_load_lds(
      (const __attribute__((address_space(1))) u32*)g,
      (__attribute__((address_space(3))) u32*)l, 16, 0, 0);
}

// --------------------------- W fp32 -> bf16 --------------------------------
__global__ __launch_bounds__(256) void wconv_kernel(
    const float* __restrict__ w0, const float* __restrict__ w1,
    const float* __restrict__ w2, u16* __restrict__ dst) {
  int p = blockIdx.y;
  const float* s = (p == 0) ? w0 : (p == 1) ? w1 : w2;
  size_t i = ((size_t)blockIdx.x * 256 + threadIdx.x) * 4;
  float4 v = *(const float4*)(s + i);
  us4 o = {f2bf(v.x), f2bf(v.y), f2bf(v.z), f2bf(v.w)};
  *(us4*)(dst + (size_t)p * CC * CC + i) = o;
}

// ------------------ x (B,C,T) fp32 -> xT (B,T,C) bf16 ----------------------
__global__ __launch_bounds__(256) void xt_kernel(
    const float* __restrict__ x, u16* __restrict__ xT) {
  __shared__ float tile[64][68];
  int t0 = blockIdx.x * 64;
  int c0 = blockIdx.y * 64;
  int b  = blockIdx.z;
  int tid = threadIdx.x;
  int lr = tid >> 4;          // 0..15
  int lc = (tid & 15) * 4;    // t within tile
  const float* src = x + ((size_t)b * CC + c0) * TT + t0;
#pragma unroll
  for (int s = 0; s < 4; ++s) {
    int c = s * 16 + lr;
    float4 v = *(const float4*)(src + (size_t)c * TT + lc);
    *(float4*)&tile[c][lc] = v;
  }
  __syncthreads();
  int t  = tid >> 2;
  int cb = (tid & 3) * 16;
  u16 tmp[16];
#pragma unroll
  for (int e = 0; e < 16; ++e) tmp[e] = f2bf(tile[cb + e][t]);
  u16* dst = xT + ((size_t)b * TT + t0 + t) * CC + c0 + cb;
  *(us8*)dst       = *(const us8*)&tmp[0];
  *(us8*)(dst + 8) = *(const us8*)&tmp[8];
}

// --------------------- QKV projection GEMM (8-phase 256^2) -----------------
// Tile: 256(o) x 256(t), BK=64, 2 K-tiles per iteration, 8 phases.
// Waves: 8 (wm in {0,1} x wn in {0..3}); wave covers m rows {f*32+wm*16},
// n cols {g*64+wn*16} so quadrant (mh,nh) reads exactly LDS half-tiles.
// LDS: A/B double-buffered [2][256][64] bf16 each = 128 KiB.
// Swizzle: stored 16B-chunk = logical_chunk ^ (row & 7)  (involution),
// applied on the READ address and inverted on the global staging SOURCE
// (global_load_lds dest must stay linear). All read rows satisfy
// row % 8 == ar % 8, so the per-thread XOR term is loop-invariant.
__global__ __launch_bounds__(512, 2) void proj_kernel(
    const u16* __restrict__ Wbf, const u16* __restrict__ xT,
    const float* __restrict__ bq, const float* __restrict__ bk,
    const float* __restrict__ bv, u16* __restrict__ qkv) {
  __shared__ __align__(16) u16 As[2][16384];
  __shared__ __align__(16) u16 Bs[2][16384];

  int tid = threadIdx.x;
  // XCD-aware bijective swizzle over 1536 = 8*192 blocks
  int bid = blockIdx.x;
  int wg  = (bid & 7) * 192 + (bid >> 3);
  int pm  = wg >> 6;            // 0..23 : proj*8 + mtile
  int b   = wg & 63;            // batch
  int proj = pm >> 3;
  int mt   = pm & 7;            // m-tile == head index
  int m0   = mt << 8;

  const u16* Ap = Wbf + (size_t)proj * CC * CC + (size_t)m0 * CC;
  const u16* Xp = xT + (size_t)b * TT * CC;
  const float* bias = (proj == 0) ? bq : (proj == 1) ? bk : bv;

  int lane = tid & 63, w = tid >> 6;
  int wm = w >> 2, wn = w & 3;
  int ar = lane & 15, kq = lane >> 4;

  // staging per-thread geometry: row r_b (0..63) within a 64-row slab,
  // 16B chunk c8; source chunk pre-swizzled (inverse of read swizzle)
  int r_b = tid >> 3;
  int c8  = tid & 7;
  int c8s = c8 ^ (r_b & 7);                 // full 3-bit XOR
  const size_t go = (size_t)r_b * CC + (size_t)c8s * 8;
  const int ldsq = r_b * 64 + c8 * 8;       // u16 units, + (h*2+j)*4096

  // read-side swizzled k-columns (bf16 units): stored chunk = kq ^ (ar&7)
  const int cx = (kq ^ (ar & 7)) * 8;       // kk=0 ; kk=1 col = cx ^ 32

  const int arow = wm * 16 + ar;            // + f*32
  const int brow = wn * 16 + ar;            // + g*64

#define STG_A(buf, kt, h)                                                     \
  do {                                                                        \
    async16(Ap + (size_t)((h) * 128) * CC + (size_t)(kt) * 64 + go,           \
            &As[buf][(h) * 8192 + ldsq]);                                     \
    async16(Ap + (size_t)((h) * 128 + 64) * CC + (size_t)(kt) * 64 + go,      \
            &As[buf][(h) * 8192 + 4096 + ldsq]);                              \
  } while (0)
#define STG_B(buf, kt, h)                                                     \
  do {                                                                        \
    async16(Xp + (size_t)((h) * 128) * CC + (size_t)(kt) * 64 + go,           \
            &Bs[buf][(h) * 8192 + ldsq]);                                     \
    async16(Xp + (size_t)((h) * 128 + 64) * CC + (size_t)(kt) * 64 + go,      \
            &Bs[buf][(h) * 8192 + 4096 + ldsq]);                              \
  } while (0)

  bf16x8 af[4][2], bfr[2][2];
  f32x4 acc[8][4] = {};

#define LDA(buf, mh)                                                          \
  do {                                                                        \
    _Pragma("unroll") for (int fl = 0; fl < 4; ++fl) {                        \
      int row = ((mh) * 4 + fl) * 32 + arow;                                  \
      af[fl][0] = *(const bf16x8*)&As[buf][row * 64 + cx];                    \
      af[fl][1] = *(const bf16x8*)&As[buf][row * 64 + (cx ^ 32)];             \
    }                                                                         \
  } while (0)
#define LDB(buf, nh)                                                          \
  do {                                                                        \
    _Pragma("unroll") for (int gl = 0; gl < 2; ++gl) {                        \
      int row = ((nh) * 2 + gl) * 64 + brow;                                  \
      bfr[gl][0] = *(const bf16x8*)&Bs[buf][row * 64 + cx];                   \
      bfr[gl][1] = *(const bf16x8*)&Bs[buf][row * 64 + (cx ^ 32)];            \
    }                                                                         \
  } while (0)
#define MMA(mh, nh)                                                           \
  do {                                                                        \
    _Pragma("unroll") for (int fl = 0; fl < 4; ++fl) {                        \
      _Pragma("unroll") for (int gl = 0; gl < 2; ++gl) {                      \
        acc[(mh) * 4 + fl][(nh) * 2 + gl] =                                   \
            __builtin_amdgcn_mfma_f32_16x16x32_bf16(                          \
                af[fl][0], bfr[gl][0], acc[(mh) * 4 + fl][(nh) * 2 + gl], 0,  \
                0, 0);                                                        \
        acc[(mh) * 4 + fl][(nh) * 2 + gl] =                                   \
            __builtin_amdgcn_mfma_f32_16x16x32_bf16(                          \
                af[fl][1], bfr[gl][1], acc[(mh) * 4 + fl][(nh) * 2 + gl], 0,  \
                0, 0);                                                        \
      }                                                                       \
    }                                                                         \
  } while (0)
#define PRE(buf, mh, nh)                                                      \
  do {                                                                        \
    if ((nh) == 0) LDA(buf, mh);                                              \
    LDB(buf, nh);                                                             \
  } while (0)
#define POST(mh, nh)                                                          \
  do {                                                                        \
    __builtin_amdgcn_s_barrier();                                             \
    asm volatile("s_waitcnt lgkmcnt(0)" ::: "memory");                        \
    __builtin_amdgcn_sched_barrier(0);                                        \
    __builtin_amdgcn_s_setprio(1);                                            \
    MMA(mh, nh);                                                              \
    __builtin_amdgcn_s_setprio(0);                                            \
    __builtin_amdgcn_sched_barrier(0);                                        \
    __builtin_amdgcn_s_barrier();                                             \
  } while (0)
#define VM4 asm volatile("s_waitcnt vmcnt(4)" ::: "memory")
#define VM0 asm volatile("s_waitcnt vmcnt(0)" ::: "memory")

  // prologue: kt0 fully (first 8 loads), then kt1 Ah0,Bh0
  STG_A(0, 0, 0); STG_B(0, 0, 0); STG_A(0, 0, 1); STG_B(0, 0, 1);
  STG_A(1, 1, 0); STG_B(1, 1, 0);
  VM4;                               // first 8 loads (kt0) landed
  __builtin_amdgcn_s_barrier();

  // main loop: iter i computes kt 2i (buf0, phases 1-4) and 2i+1 (buf1, 5-8).
  // Stage placement: each half-tile is overwritten >=1 full phase after its
  // last read; vmcnt(4) at p4/p8 proves the next K-tile landed.
  for (int i = 0; i < 15; ++i) {
    int k = 2 * i;
    PRE(0, 0, 0); STG_A(1, k + 1, 1);      POST(0, 0);   // p1
    PRE(0, 0, 1); STG_B(1, k + 1, 1);      POST(0, 1);   // p2
    PRE(0, 1, 0); STG_A(0, k + 2, 0);      POST(1, 0);   // p3
    PRE(0, 1, 1); STG_B(0, k + 2, 0); VM4; POST(1, 1);   // p4
    PRE(1, 0, 0); STG_A(0, k + 2, 1);      POST(0, 0);   // p5
    PRE(1, 0, 1); STG_B(0, k + 2, 1);      POST(0, 1);   // p6
    PRE(1, 1, 0); STG_A(1, k + 3, 0);      POST(1, 0);   // p7
    PRE(1, 1, 1); STG_B(1, k + 3, 0); VM4; POST(1, 1);   // p8
  }
  // peeled last iteration: kt30 (buf0), kt31 (buf1); finish kt31 staging
  PRE(0, 0, 0); STG_A(1, 31, 1);           POST(0, 0);
  PRE(0, 0, 1); STG_B(1, 31, 1);           POST(0, 1);
  PRE(0, 1, 0);                            POST(1, 0);
  PRE(0, 1, 1);                       VM0; POST(1, 1);
  PRE(1, 0, 0);                            POST(0, 0);
  PRE(1, 0, 1);                            POST(0, 1);
  PRE(1, 1, 0);                            POST(1, 0);
  PRE(1, 1, 1);                            POST(1, 1);

  // epilogue: C row (o) = f*32 + wm*16 + kq*4 + r ; col (t) = g*64 + wn*16 + ar
  // store transposed into qkv[proj][b][head=mt][t][d], bias added, bf16.
  u16* outp = qkv + (size_t)proj * BB * CC * TT +
              (size_t)(b * HH + mt) * TT * DD;
#pragma unroll
  for (int f = 0; f < 8; ++f) {
    int d0 = f * 32 + wm * 16 + kq * 4;
    float b0 = bias[m0 + d0],     b1 = bias[m0 + d0 + 1];
    float b2 = bias[m0 + d0 + 2], b3 = bias[m0 + d0 + 3];
#pragma unroll
    for (int g = 0; g < 4; ++g) {
      int t = g * 64 + wn * 16 + ar;
      f32x4 v = acc[f][g];
      us4 pk = {f2bf(v[0] + b0), f2bf(v[1] + b1), f2bf(v[2] + b2),
                f2bf(v[3] + b3)};
      *(us4*)(outp + (size_t)t * DD + d0) = pk;
    }
  }
#undef STG_A
#undef STG_B
#undef LDA
#undef LDB
#undef MMA
#undef PRE
#undef POST
#undef VM4
#undef VM0
}

// ----------------------------- fused attention -----------------------------
// block: one (b,h) pair, 64 q-rows. Phase1 S=QK^T in regs; exp (no max
// subtraction -- logits are O(1)); P bf16 -> padded LDS; rowsums via
// shfl_xor + LDS; Phase2 O = P V^T; epilogue multiplies by 1/rowsum.
__global__ __launch_bounds__(256) void attn_kernel(
    const u16* __restrict__ qkv, float* __restrict__ out) {
  __shared__ __align__(16) u16 As[64 * 32];
  __shared__ __align__(16) u16 Bs[256 * 32];
  __shared__ __align__(16) u16 Ps[64 * 264];   // +8 pad: 2-way banks only
  __shared__ float rowpart[64][4];
  __shared__ float inv[64];

  int tid = threadIdx.x;
  int i0 = blockIdx.x * 64;
  int bh = blockIdx.y;                          // b*8 + h
  const size_t hd = (size_t)TT * DD;            // 65536
  const u16* Q = qkv + (size_t)bh * hd;
  const u16* K = qkv + (size_t)(BB * HH + bh) * hd;
  const u16* V = qkv + (size_t)(2 * BB * HH + bh) * hd;

  int lane = tid & 63, w = tid >> 6;
  int ar = lane & 15, kq = lane >> 4;
  int arow = tid >> 2, acol = (tid & 3) * 8;

  const u16* Qbase = Q + (size_t)(i0 + arow) * DD + acol;
  const u16* Kbase = K + (size_t)arow * DD + acol;
  const u16* Vbase = V + (size_t)arow * DD + acol;

  f32x4 acc[4][4] = {};
  // ---- phase 1: S = Q K^T ----
  for (int k0 = 0; k0 < DD; k0 += 32) {
    async16(Qbase + k0, As + tid * 8);
#pragma unroll
    for (int s = 0; s < 4; ++s)
      async16(Kbase + (size_t)(s * 64) * DD + k0, Bs + s * 2048 + tid * 8);
    __syncthreads();
    bf16x8 af[4], bfv[4];
#pragma unroll
    for (int mt = 0; mt < 4; ++mt)
      af[mt] = *(const bf16x8*)&As[(mt * 16 + ar) * 32 + kq * 8];
#pragma unroll
    for (int nt = 0; nt < 4; ++nt)
      bfv[nt] = *(const bf16x8*)&Bs[(w * 64 + nt * 16 + ar) * 32 + kq * 8];
#pragma unroll
    for (int mt = 0; mt < 4; ++mt)
#pragma unroll
      for (int nt = 0; nt < 4; ++nt)
        acc[mt][nt] = __builtin_amdgcn_mfma_f32_16x16x32_bf16(
            af[mt], bfv[nt], acc[mt][nt], 0, 0, 0);
    __syncthreads();
  }
  // ---- exp + P to LDS + row partial sums ----
  const float scale = 0.0625f;
#pragma unroll
  for (int mt = 0; mt < 4; ++mt) {
    float ps[4] = {0.f, 0.f, 0.f, 0.f};
#pragma unroll
    for (int nt = 0; nt < 4; ++nt) {
      f32x4 v = acc[mt][nt];
#pragma unroll
      for (int r = 0; r < 4; ++r) {
        float p = __expf(v[r] * scale);
        u16 pb = f2bf(p);
        Ps[(mt * 16 + kq * 4 + r) * 264 + (w * 64 + nt * 16 + ar)] = pb;
        ps[r] += bf2f(pb);   // sum the rounded value for consistency
      }
    }
#pragma unroll
    for (int r = 0; r < 4; ++r) {
      float s = ps[r];
      s += __shfl_xor(s, 1, 64);
      s += __shfl_xor(s, 2, 64);
      s += __shfl_xor(s, 4, 64);
      s += __shfl_xor(s, 8, 64);
      if (ar == 0) rowpart[mt * 16 + kq * 4 + r][w] = s;
    }
  }
  __syncthreads();
  if (tid < 64) {
    float s = rowpart[tid][0] + rowpart[tid][1] + rowpart[tid][2] +
              rowpart[tid][3];
    inv[tid] = 1.0f / s;
  }
  // ---- phase 2: O = P V^T ----
#pragma unroll
  for (int mt = 0; mt < 4; ++mt)
#pragma unroll
    for (int nt = 0; nt < 4; ++nt) acc[mt][nt] = (f32x4){0.f, 0.f, 0.f, 0.f};
  for (int k0 = 0; k0 < TT; k0 += 32) {
#pragma unroll
    for (int s = 0; s < 4; ++s)
      async16(Vbase + (size_t)(s * 64) * DD + k0, Bs + s * 2048 + tid * 8);
    __syncthreads();
    bf16x8 af[4], bfv[4];
#pragma unroll
    for (int mt = 0; mt < 4; ++mt)
      af[mt] = *(const bf16x8*)&Ps[(mt * 16 + ar) * 264 + k0 + kq * 8];
#pragma unroll
    for (int nt = 0; nt < 4; ++nt)
      bfv[nt] = *(const bf16x8*)&Bs[(w * 64 + nt * 16 + ar) * 32 + kq * 8];
#pragma unroll
    for (int mt = 0; mt < 4; ++mt)
#pragma unroll
      for (int nt = 0; nt < 4; ++nt)
        acc[mt][nt] = __builtin_amdgcn_mfma_f32_16x16x32_bf16(
            af[mt], bfv[nt], acc[mt][nt], 0, 0, 0);
    __syncthreads();
  }
  // ---- epilogue: normalize rows, store fp32 ----
  int b = bh >> 3, h = bh & 7;
  float* obase = out + ((size_t)b * CC + h * TT + i0) * TT;
#pragma unroll
  for (int mt = 0; mt < 4; ++mt)
#pragma unroll
    for (int r = 0; r < 4; ++r) {
      int m = mt * 16 + kq * 4 + r;
      float iv = inv[m];
#pragma unroll
      for (int nt = 0; nt < 4; ++nt) {
        int n = w * 64 + nt * 16 + ar;
        obase[(size_t)m * TT + n] = acc[mt][nt][r] * iv;
      }
    }
}

// ---------------------------------------------------------------------------
extern "C" void kernel_launch(void* const* d_in, const int* in_sizes, int n_in,
                              void* d_out, int out_size, void* d_ws,
                              size_t ws_size, hipStream_t stream) {
  const float* x  = (const float*)d_in[0];
  const float* Wq = (const float*)d_in[1];
  const float* bq = (const float*)d_in[2];
  const float* Wk = (const float*)d_in[3];
  const float* bk = (const float*)d_in[4];
  const float* Wv = (const float*)d_in[5];
  const float* bv = (const float*)d_in[6];
  float* out = (float*)d_out;

  char* ws = (char*)d_ws;
  u16* xT  = (u16*)ws;                               // 64 MiB
  u16* Wbf = (u16*)(ws + 67108864);                  // 24 MiB
  u16* qkv = (u16*)(ws + 67108864 + 25165824);       // 192 MiB

  wconv_kernel<<<dim3(4096, 3, 1), 256, 0, stream>>>(Wq, Wk, Wv, Wbf);
  xt_kernel<<<dim3(4, 32, 64), 256, 0, stream>>>(x, xT);
  proj_kernel<<<dim3(1536, 1, 1), 512, 0, stream>>>(Wbf, xT, bq, bk, bv, qkv);
  attn_kernel<<<dim3(4, 512, 1), 256, 0, stream>>>(qkv, out);
}

// Round 4
// 814.653 us; speedup vs baseline: 1.1332x; 1.0465x over previous
//
#include <hip/hip_runtime.h>

// ---------------------------------------------------------------------------
// TemporalAttentionModule: B=64, C=2048, T=256, H=8, D=256 (== T)
//   q/k/v = W @ x + b   (per-batch GEMM, K=2048)
//   attn  = softmax(q k^T / 16);  out = attn @ v  -> (B, C, T) fp32
//
// ws layout (bytes):
//   [0,            67108864)  xT  bf16 [B][T][C]   (x transposed, k-major)
//   [67108864,     92274688)  Wbf bf16 [3][C][C]
//   [92274688,    293601280)  qkv bf16 [3][B][H][T][D]  (all stored d-major;
//                             for V this is V^T so PV is also a gemm_bt)
//
// proj_kernel: 256x256-tile, BK=64, 4 fat phases per 2 K-tiles (mh-split),
// B-fragments loaded ONCE per K-tile (bfr[4][2] held across both phases),
// full 3-bit chunk-XOR LDS swizzle (conflict-free, verified R1: 5e7 -> 0),
// counted vmcnt, setprio around MFMA. 512 threads, 128 KiB LDS.
// (Resubmission of R2 source: bench infra failed, no measurement obtained.)
// ---------------------------------------------------------------------------

typedef __attribute__((ext_vector_type(8))) short    bf16x8;
typedef __attribute__((ext_vector_type(4))) float    f32x4;
typedef __attribute__((ext_vector_type(4))) unsigned short us4;
typedef __attribute__((ext_vector_type(8))) unsigned short us8;
typedef unsigned short u16;
typedef unsigned int   u32;

#define CC 2048
#define TT 256
#define BB 64
#define HH 8
#define DD 256

__device__ __forceinline__ u16 f2bf(float f) {
  u32 u = __builtin_bit_cast(u32, f);
  u32 r = (u + 0x7fffu + ((u >> 16) & 1u)) >> 16;
  return (u16)r;
}
__device__ __forceinline__ float bf2f(u16 b) {
  u32 u = ((u32)b) << 16;
  return __builtin_bit_cast(float, u);
}

__device__ __forceinline__ void async16(const void* g, void* l) {
  __builtin_amdgcn_global_load_lds(
      (const __attribute__((address_space(1))) u32*)g,
      (__attribute__((address_space(3))) u32*)l, 16, 0, 0);
}

// --------------------------- W fp32 -> bf16 --------------------------------
__global__ __launch_bounds__(256) void wconv_kernel(
    const float* __restrict__ w0, const float* __restrict__ w1,
    const float* __restrict__ w2, u16* __restrict__ dst) {
  int p = blockIdx.y;
  const float* s = (p == 0) ? w0 : (p == 1) ? w1 : w2;
  size_t i = ((size_t)blockIdx.x * 256 + threadIdx.x) * 4;
  float4 v = *(const float4*)(s + i);
  us4 o = {f2bf(v.x), f2bf(v.y), f2bf(v.z), f2bf(v.w)};
  *(us4*)(dst + (size_t)p * CC * CC + i) = o;
}

// ------------------ x (B,C,T) fp32 -> xT (B,T,C) bf16 ----------------------
__global__ __launch_bounds__(256) void xt_kernel(
    const float* __restrict__ x, u16* __restrict__ xT) {
  __shared__ float tile[64][68];
  int t0 = blockIdx.x * 64;
  int c0 = blockIdx.y * 64;
  int b  = blockIdx.z;
  int tid = threadIdx.x;
  int lr = tid >> 4;          // 0..15
  int lc = (tid & 15) * 4;    // t within tile
  const float* src = x + ((size_t)b * CC + c0) * TT + t0;
#pragma unroll
  for (int s = 0; s < 4; ++s) {
    int c = s * 16 + lr;
    float4 v = *(const float4*)(src + (size_t)c * TT + lc);
    *(float4*)&tile[c][lc] = v;
  }
  __syncthreads();
  int t  = tid >> 2;
  int cb = (tid & 3) * 16;
  u16 tmp[16];
#pragma unroll
  for (int e = 0; e < 16; ++e) tmp[e] = f2bf(tile[cb + e][t]);
  u16* dst = xT + ((size_t)b * TT + t0 + t) * CC + c0 + cb;
  *(us8*)dst       = *(const us8*)&tmp[0];
  *(us8*)(dst + 8) = *(const us8*)&tmp[8];
}

// --------------------- QKV projection GEMM (4-fat-phase 256^2) -------------
// Waves: 8 (wm in {0,1} x wn in {0..3}); per-wave output 128x64.
// Per K-tile: 2 phases (mh = A-half). Phase reads: F-even: LDA(mh0) 8 +
// LDBALL 8 = 16 b128; F-odd: LDA(mh1) 8. B frags live across both phases
// (loaded once per K-tile = minimal LDS traffic: 24 b128/wave/K-tile).
// Staging (per iter i, kt=2i): F1<-kt+1{Bh1,Ah1}, F2<-kt+2{Ah0,Bh0},
// F3<-kt+2{Bh1,Ah1}, F4<-kt+3{Ah0,Bh0}; every writer issues >=1 barrier
// after its region's last reader drained; vmcnt(4) at end of F2/F4 proves
// the tile consumed by the NEXT phase has landed (12 outstanding -> oldest
// 8 done).
__global__ __launch_bounds__(512, 2) void proj_kernel(
    const u16* __restrict__ Wbf, const u16* __restrict__ xT,
    const float* __restrict__ bq, const float* __restrict__ bk,
    const float* __restrict__ bv, u16* __restrict__ qkv) {
  __shared__ __align__(16) u16 As[2][16384];
  __shared__ __align__(16) u16 Bs[2][16384];

  int tid = threadIdx.x;
  // XCD-aware bijective swizzle over 1536 = 8*192 blocks
  int bid = blockIdx.x;
  int wg  = (bid & 7) * 192 + (bid >> 3);
  int pm  = wg >> 6;            // 0..23 : proj*8 + mtile
  int b   = wg & 63;            // batch
  int proj = pm >> 3;
  int mt   = pm & 7;            // m-tile == head index
  int m0   = mt << 8;

  const u16* Ap = Wbf + (size_t)proj * CC * CC + (size_t)m0 * CC;
  const u16* Xp = xT + (size_t)b * TT * CC;
  const float* bias = (proj == 0) ? bq : (proj == 1) ? bk : bv;

  int lane = tid & 63, w = tid >> 6;
  int wm = w >> 2, wn = w & 3;
  int ar = lane & 15, kq = lane >> 4;

  // staging per-thread geometry: row r_b (0..63) within a 64-row slab,
  // 16B chunk c8; source chunk pre-swizzled (inverse of read swizzle)
  int r_b = tid >> 3;
  int c8  = tid & 7;
  int c8s = c8 ^ (r_b & 7);                 // full 3-bit XOR
  const size_t go = (size_t)r_b * CC + (size_t)c8s * 8;
  const int ldsq = r_b * 64 + c8 * 8;       // u16 units, + (h*2+j)*4096

  // read-side swizzled k-columns (bf16 units): stored chunk = kq ^ (ar&7)
  const int cx = (kq ^ (ar & 7)) * 8;       // kk=0 ; kk=1 col = cx ^ 32

  const int arow = wm * 16 + ar;            // + f*32
  const int brow = wn * 16 + ar;            // + g*64

#define STG_A(buf, kt, h)                                                     \
  do {                                                                        \
    async16(Ap + (size_t)((h) * 128) * CC + (size_t)(kt) * 64 + go,           \
            &As[buf][(h) * 8192 + ldsq]);                                     \
    async16(Ap + (size_t)((h) * 128 + 64) * CC + (size_t)(kt) * 64 + go,      \
            &As[buf][(h) * 8192 + 4096 + ldsq]);                              \
  } while (0)
#define STG_B(buf, kt, h)                                                     \
  do {                                                                        \
    async16(Xp + (size_t)((h) * 128) * CC + (size_t)(kt) * 64 + go,           \
            &Bs[buf][(h) * 8192 + ldsq]);                                     \
    async16(Xp + (size_t)((h) * 128 + 64) * CC + (size_t)(kt) * 64 + go,      \
            &Bs[buf][(h) * 8192 + 4096 + ldsq]);                              \
  } while (0)

  bf16x8 af[4][2], bfr[4][2];
  f32x4 acc[8][4] = {};

#define LDA(buf, mh)                                                          \
  do {                                                                        \
    _Pragma("unroll") for (int fl = 0; fl < 4; ++fl) {                        \
      int row = ((mh) * 4 + fl) * 32 + arow;                                  \
      af[fl][0] = *(const bf16x8*)&As[buf][row * 64 + cx];                    \
      af[fl][1] = *(const bf16x8*)&As[buf][row * 64 + (cx ^ 32)];             \
    }                                                                         \
  } while (0)
#define LDBALL(buf)                                                           \
  do {                                                                        \
    _Pragma("unroll") for (int g = 0; g < 4; ++g) {                           \
      int row = g * 64 + brow;                                                \
      bfr[g][0] = *(const bf16x8*)&Bs[buf][row * 64 + cx];                    \
      bfr[g][1] = *(const bf16x8*)&Bs[buf][row * 64 + (cx ^ 32)];             \
    }                                                                         \
  } while (0)
#define MMA_MH(mh)                                                            \
  do {                                                                        \
    _Pragma("unroll") for (int fl = 0; fl < 4; ++fl) {                        \
      _Pragma("unroll") for (int g = 0; g < 4; ++g) {                         \
        acc[(mh) * 4 + fl][g] = __builtin_amdgcn_mfma_f32_16x16x32_bf16(      \
            af[fl][0], bfr[g][0], acc[(mh) * 4 + fl][g], 0, 0, 0);            \
        acc[(mh) * 4 + fl][g] = __builtin_amdgcn_mfma_f32_16x16x32_bf16(      \
            af[fl][1], bfr[g][1], acc[(mh) * 4 + fl][g], 0, 0, 0);            \
      }                                                                       \
    }                                                                         \
  } while (0)
#define POSTF(mh)                                                             \
  do {                                                                        \
    __builtin_amdgcn_s_barrier();                                             \
    asm volatile("s_waitcnt lgkmcnt(0)" ::: "memory");                        \
    __builtin_amdgcn_sched_barrier(0);                                        \
    __builtin_amdgcn_s_setprio(1);                                            \
    MMA_MH(mh);                                                               \
    __builtin_amdgcn_s_setprio(0);                                            \
    __builtin_amdgcn_sched_barrier(0);                                        \
    __builtin_amdgcn_s_barrier();                                             \
  } while (0)
#define VM4 asm volatile("s_waitcnt vmcnt(4)" ::: "memory")
#define VM0 asm volatile("s_waitcnt vmcnt(0)" ::: "memory")

  // prologue: kt0 full (8 loads) + kt1 h0 halves (4 loads)
  STG_A(0, 0, 0); STG_B(0, 0, 0); STG_A(0, 0, 1); STG_B(0, 0, 1);
  STG_A(1, 1, 0); STG_B(1, 1, 0);
  VM4;                               // kt0's 8 loads landed
  __builtin_amdgcn_s_barrier();

  // main loop: iter i computes kt=2i (buf0: F1,F2) and kt=2i+1 (buf1: F3,F4)
  for (int i = 0; i < 15; ++i) {
    int k = 2 * i;
    // F1: buf0 mh0 (reads A0h0 + B0 all)
    LDA(0, 0); LDBALL(0);
    STG_B(1, k + 1, 1); STG_A(1, k + 1, 1);
    POSTF(0);
    // F2: buf0 mh1 (reads A0h1; B frags still live)
    LDA(0, 1);
    STG_A(0, k + 2, 0); STG_B(0, k + 2, 0);
    VM4;                             // kt+1 fully landed for F3
    POSTF(1);
    // F3: buf1 mh0
    LDA(1, 0); LDBALL(1);
    STG_B(0, k + 2, 1); STG_A(0, k + 2, 1);
    POSTF(0);
    // F4: buf1 mh1
    LDA(1, 1);
    STG_A(1, k + 3, 0); STG_B(1, k + 3, 0);
    VM4;                             // kt+2 fully landed for next F1
    POSTF(1);
  }
  // peeled last iteration: kt30 (buf0), kt31 (buf1)
  LDA(0, 0); LDBALL(0);
  STG_B(1, 31, 1); STG_A(1, 31, 1);
  POSTF(0);
  LDA(0, 1);
  VM0;                               // kt31 fully landed for F3p
  POSTF(1);
  LDA(1, 0); LDBALL(1);
  POSTF(0);
  LDA(1, 1);
  POSTF(1);

  // epilogue: C row (o) = f*32 + wm*16 + kq*4 + r ; col (t) = g*64 + wn*16 + ar
  // store transposed into qkv[proj][b][head=mt][t][d], bias added, bf16.
  u16* outp = qkv + (size_t)proj * BB * CC * TT +
              (size_t)(b * HH + mt) * TT * DD;
#pragma unroll
  for (int f = 0; f < 8; ++f) {
    int d0 = f * 32 + wm * 16 + kq * 4;
    float b0 = bias[m0 + d0],     b1 = bias[m0 + d0 + 1];
    float b2 = bias[m0 + d0 + 2], b3 = bias[m0 + d0 + 3];
#pragma unroll
    for (int g = 0; g < 4; ++g) {
      int t = g * 64 + wn * 16 + ar;
      f32x4 v = acc[f][g];
      us4 pk = {f2bf(v[0] + b0), f2bf(v[1] + b1), f2bf(v[2] + b2),
                f2bf(v[3] + b3)};
      *(us4*)(outp + (size_t)t * DD + d0) = pk;
    }
  }
#undef STG_A
#undef STG_B
#undef LDA
#undef LDBALL
#undef MMA_MH
#undef POSTF
#undef VM4
#undef VM0
}

// ----------------------------- fused attention -----------------------------
// block: one (b,h) pair, 64 q-rows. Phase1 S=QK^T in regs; exp (no max
// subtraction -- logits are O(1)); P bf16 -> padded LDS; rowsums via
// shfl_xor + LDS; Phase2 O = P V^T; epilogue multiplies by 1/rowsum.
__global__ __launch_bounds__(256) void attn_kernel(
    const u16* __restrict__ qkv, float* __restrict__ out) {
  __shared__ __align__(16) u16 As[64 * 32];
  __shared__ __align__(16) u16 Bs[256 * 32];
  __shared__ __align__(16) u16 Ps[64 * 264];   // +8 pad: 2-way banks only
  __shared__ float rowpart[64][4];
  __shared__ float inv[64];

  int tid = threadIdx.x;
  int i0 = blockIdx.x * 64;
  int bh = blockIdx.y;                          // b*8 + h
  const size_t hd = (size_t)TT * DD;            // 65536
  const u16* Q = qkv + (size_t)bh * hd;
  const u16* K = qkv + (size_t)(BB * HH + bh) * hd;
  const u16* V = qkv + (size_t)(2 * BB * HH + bh) * hd;

  int lane = tid & 63, w = tid >> 6;
  int ar = lane & 15, kq = lane >> 4;
  int arow = tid >> 2, acol = (tid & 3) * 8;

  const u16* Qbase = Q + (size_t)(i0 + arow) * DD + acol;
  const u16* Kbase = K + (size_t)arow * DD + acol;
  const u16* Vbase = V + (size_t)arow * DD + acol;

  f32x4 acc[4][4] = {};
  // ---- phase 1: S = Q K^T ----
  for (int k0 = 0; k0 < DD; k0 += 32) {
    async16(Qbase + k0, As + tid * 8);
#pragma unroll
    for (int s = 0; s < 4; ++s)
      async16(Kbase + (size_t)(s * 64) * DD + k0, Bs + s * 2048 + tid * 8);
    __syncthreads();
    bf16x8 af[4], bfv[4];
#pragma unroll
    for (int mt = 0; mt < 4; ++mt)
      af[mt] = *(const bf16x8*)&As[(mt * 16 + ar) * 32 + kq * 8];
#pragma unroll
    for (int nt = 0; nt < 4; ++nt)
      bfv[nt] = *(const bf16x8*)&Bs[(w * 64 + nt * 16 + ar) * 32 + kq * 8];
#pragma unroll
    for (int mt = 0; mt < 4; ++mt)
#pragma unroll
      for (int nt = 0; nt < 4; ++nt)
        acc[mt][nt] = __builtin_amdgcn_mfma_f32_16x16x32_bf16(
            af[mt], bfv[nt], acc[mt][nt], 0, 0, 0);
    __syncthreads();
  }
  // ---- exp + P to LDS + row partial sums ----
  const float scale = 0.0625f;
#pragma unroll
  for (int mt = 0; mt < 4; ++mt) {
    float ps[4] = {0.f, 0.f, 0.f, 0.f};
#pragma unroll
    for (int nt = 0; nt < 4; ++nt) {
      f32x4 v = acc[mt][nt];
#pragma unroll
      for (int r = 0; r < 4; ++r) {
        float p = __expf(v[r] * scale);
        u16 pb = f2bf(p);
        Ps[(mt * 16 + kq * 4 + r) * 264 + (w * 64 + nt * 16 + ar)] = pb;
        ps[r] += bf2f(pb);   // sum the rounded value for consistency
      }
    }
#pragma unroll
    for (int r = 0; r < 4; ++r) {
      float s = ps[r];
      s += __shfl_xor(s, 1, 64);
      s += __shfl_xor(s, 2, 64);
      s += __shfl_xor(s, 4, 64);
      s += __shfl_xor(s, 8, 64);
      if (ar == 0) rowpart[mt * 16 + kq * 4 + r][w] = s;
    }
  }
  __syncthreads();
  if (tid < 64) {
    float s = rowpart[tid][0] + rowpart[tid][1] + rowpart[tid][2] +
              rowpart[tid][3];
    inv[tid] = 1.0f / s;
  }
  // ---- phase 2: O = P V^T ----
#pragma unroll
  for (int mt = 0; mt < 4; ++mt)
#pragma unroll
    for (int nt = 0; nt < 4; ++nt) acc[mt][nt] = (f32x4){0.f, 0.f, 0.f, 0.f};
  for (int k0 = 0; k0 < TT; k0 += 32) {
#pragma unroll
    for (int s = 0; s < 4; ++s)
      async16(Vbase + (size_t)(s * 64) * DD + k0, Bs + s * 2048 + tid * 8);
    __syncthreads();
    bf16x8 af[4], bfv[4];
#pragma unroll
    for (int mt = 0; mt < 4; ++mt)
      af[mt] = *(const bf16x8*)&Ps[(mt * 16 + ar) * 264 + k0 + kq * 8];
#pragma unroll
    for (int nt = 0; nt < 4; ++nt)
      bfv[nt] = *(const bf16x8*)&Bs[(w * 64 + nt * 16 + ar) * 32 + kq * 8];
#pragma unroll
    for (int mt = 0; mt < 4; ++mt)
#pragma unroll
      for (int nt = 0; nt < 4; ++nt)
        acc[mt][nt] = __builtin_amdgcn_mfma_f32_16x16x32_bf16(
            af[mt], bfv[nt], acc[mt][nt], 0, 0, 0);
    __syncthreads();
  }
  // ---- epilogue: normalize rows, store fp32 ----
  int b = bh >> 3, h = bh & 7;
  float* obase = out + ((size_t)b * CC + h * TT + i0) * TT;
#pragma unroll
  for (int mt = 0; mt < 4; ++mt)
#pragma unroll
    for (int r = 0; r < 4; ++r) {
      int m = mt * 16 + kq * 4 + r;
      float iv = inv[m];
#pragma unroll
      for (int nt = 0; nt < 4; ++nt) {
        int n = w * 64 + nt * 16 + ar;
        obase[(size_t)m * TT + n] = acc[mt][nt][r] * iv;
      }
    }
}

// ---------------------------------------------------------------------------
extern "C" void kernel_launch(void* const* d_in, const int* in_sizes, int n_in,
                              void* d_out, int out_size, void* d_ws,
                              size_t ws_size, hipStream_t stream) {
  const float* x  = (const float*)d_in[0];
  const float* Wq = (const float*)d_in[1];
  const float* bq = (const float*)d_in[2];
  const float* Wk = (const float*)d_in[3];
  const float* bk = (const float*)d_in[4];
  const float* Wv = (const float*)d_in[5];
  const float* bv = (const float*)d_in[6];
  float* out = (float*)d_out;

  char* ws = (char*)d_ws;
  u16* xT  = (u16*)ws;                               // 64 MiB
  u16* Wbf = (u16*)(ws + 67108864);                  // 24 MiB
  u16* qkv = (u16*)(ws + 67108864 + 25165824);       // 192 MiB

  wconv_kernel<<<dim3(4096, 3, 1), 256, 0, stream>>>(Wq, Wk, Wv, Wbf);
  xt_kernel<<<dim3(4, 32, 64), 256, 0, stream>>>(x, xT);
  proj_kernel<<<dim3(1536, 1, 1), 512, 0, stream>>>(Wbf, xT, bq, bk, bv, qkv);
  attn_kernel<<<dim3(4, 512, 1), 256, 0, stream>>>(qkv, out);
}